// Round 6
// baseline (81.753 us; speedup 1.0000x reference)
//
#include <hip/hip_runtime.h>
#include <hip/hip_bf16.h>

#define S 1024
#define C 384
#define NC 32
#define SHIFT 0.3f

typedef __attribute__((ext_vector_type(4))) float f32x4;
typedef __attribute__((ext_vector_type(8))) short short8;

// f32 -> bf16 (round-to-nearest-even), raw-bit version (finite inputs only)
__device__ __forceinline__ unsigned int f2bf(float x) {
  unsigned int u = __builtin_bit_cast(unsigned int, x);
  unsigned int rb = ((u >> 16) & 1u) + 0x7fffu;
  return (u + rb) >> 16;
}
__device__ __forceinline__ unsigned int f2bf2(float lo, float hi) {
  return f2bf(lo) | (f2bf(hi) << 16);
}

// ---- prep: normalize f -> bf16 fnb; exp(p)/p -> bf16 Eb/Pb; rowdot ----
__global__ __launch_bounds__(256) void k_prep(const float* __restrict__ f,
                                              const float* __restrict__ p,
                                              unsigned int* __restrict__ fnb,
                                              unsigned int* __restrict__ Eb,
                                              unsigned int* __restrict__ Pb,
                                              float* __restrict__ rowdot) {
  if (blockIdx.x < 1024) {
    // one wave per feat row: sum squares, scale, pack bf16
    int lane = threadIdx.x & 63;
    int row = blockIdx.x * 4 + (threadIdx.x >> 6);
    const float* fr = f + (size_t)row * C;
    float2 v[3];
    float ss = 0.f;
#pragma unroll
    for (int j = 0; j < 3; ++j) {
      v[j] = *(const float2*)(fr + 2 * lane + 128 * j);
      ss = fmaf(v[j].x, v[j].x, fmaf(v[j].y, v[j].y, ss));
    }
#pragma unroll
    for (int m = 32; m >= 1; m >>= 1) ss += __shfl_xor(ss, m, 64);
    float s = 1.f / fmaxf(sqrtf(ss), 1e-12f);
    unsigned int* outr = fnb + (size_t)row * (C / 2);
#pragma unroll
    for (int j = 0; j < 3; ++j) outr[lane + 64 * j] = f2bf2(v[j].x * s, v[j].y * s);
  } else {
    // 4 threads per p-row: pack exp(p) and p to bf16, reduce rowdot
    int t = (blockIdx.x - 1024) * 256 + threadIdx.x;  // [0, 16384)
    int r = t >> 2, q = t & 3;
    const float* pr = p + (size_t)r * NC + q * 8;
    float4 a = *(const float4*)pr;
    float4 b = *(const float4*)(pr + 4);
    float ea0 = __expf(a.x), ea1 = __expf(a.y), ea2 = __expf(a.z), ea3 = __expf(a.w);
    float eb0 = __expf(b.x), eb1 = __expf(b.y), eb2 = __expf(b.z), eb3 = __expf(b.w);
    uint4 ue = make_uint4(f2bf2(ea0, ea1), f2bf2(ea2, ea3), f2bf2(eb0, eb1), f2bf2(eb2, eb3));
    uint4 up = make_uint4(f2bf2(a.x, a.y), f2bf2(a.z, a.w), f2bf2(b.x, b.y), f2bf2(b.z, b.w));
    *(uint4*)(Eb + r * 16 + q * 4) = ue;
    *(uint4*)(Pb + r * 16 + q * 4) = up;
    float s = ea0 * a.x + ea1 * a.y + ea2 * a.z + ea3 * a.w +
              eb0 * b.x + eb1 * b.y + eb2 * b.z + eb3 * b.w;
    s += __shfl_xor(s, 1, 64);
    s += __shfl_xor(s, 2, 64);
    if (q == 0) rowdot[r] = s;
  }
}

// ---- pairwise: 64x128 tile, NO LDS / NO barriers ----
// MFMA fragments loaded directly from global: for 16x16x32 bf16, lane (lan,quad)
// holds A[m=lan][k=quad*8..+7] = 16 contiguous bytes; lanes lan,lan+16,lan+32,lan+48
// cover one row's 64 contiguous bytes -> clean 64B-line requests, L1/L2-resident.
// Waves free-run; compiler pipelines loads across unrolled K-steps (no vmcnt(0) drain).
__global__ __launch_bounds__(256) void k_pair(
    const unsigned short* __restrict__ fnb, const unsigned short* __restrict__ Eb,
    const unsigned short* __restrict__ Pb, const float* __restrict__ rowdot,
    float* __restrict__ partials) {
  const int tid = threadIdx.x;
  const int lane = tid & 63;
  const int wave = tid >> 6;
  const int lan = lane & 15, quad = lane >> 4;
  const int n = blockIdx.z;
  const int sBase = blockIdx.y * 64;   // A rows (s)
  const int lBase = blockIdx.x * 128;  // B rows (l); wave owns cols [32*wave, 32*wave+32)

  const unsigned short* baseA = fnb + (size_t)(n * S + sBase + lan) * C + quad * 8;
  const unsigned short* baseB = fnb + (size_t)(n * S + lBase + wave * 32 + lan) * C + quad * 8;

  f32x4 acc[4][2];
#pragma unroll
  for (int i = 0; i < 4; ++i)
#pragma unroll
    for (int j = 0; j < 2; ++j) acc[i][j] = (f32x4){0.f, 0.f, 0.f, 0.f};

  // K loop: 12 steps of K=32; 6 fragment loads + 8 MFMA per step
#pragma unroll 4
  for (int ks = 0; ks < 12; ++ks) {
    short8 af[4], bfr[2];
#pragma unroll
    for (int t = 0; t < 4; ++t) af[t] = *(const short8*)(baseA + t * 16 * C + ks * 32);
#pragma unroll
    for (int t = 0; t < 2; ++t) bfr[t] = *(const short8*)(baseB + t * 16 * C + ks * 32);
#pragma unroll
    for (int i = 0; i < 4; ++i)
#pragma unroll
      for (int j = 0; j < 2; ++j)
        acc[i][j] = __builtin_amdgcn_mfma_f32_16x16x32_bf16(af[i], bfr[j], acc[i][j], 0, 0, 0);
  }

  // epilogue: EP mini-GEMM (K=NC=32, direct-loaded fragments) + masked reduction
  // C/D layout col=lane&15, row=quad*4+reg
  short8 ea[4], pb[2];
  const unsigned short* baseE = Eb + (size_t)(n * S + sBase + lan) * NC + quad * 8;
  const unsigned short* baseP = Pb + (size_t)(n * S + lBase + wave * 32 + lan) * NC + quad * 8;
#pragma unroll
  for (int t = 0; t < 4; ++t) ea[t] = *(const short8*)(baseE + t * 16 * NC);
#pragma unroll
  for (int t = 0; t < 2; ++t) pb[t] = *(const short8*)(baseP + t * 16 * NC);

  float pos_s = 0.f, neg_s = 0.f, posc = 0.f, negc = 0.f;
#pragma unroll
  for (int i = 0; i < 4; ++i) {
    float rd[4];
    int gs = n * S + sBase + i * 16 + quad * 4;
#pragma unroll
    for (int r = 0; r < 4; ++r) rd[r] = rowdot[gs + r];
#pragma unroll
    for (int j = 0; j < 2; ++j) {
      f32x4 z = (f32x4){0.f, 0.f, 0.f, 0.f};
      f32x4 ep = __builtin_amdgcn_mfma_f32_16x16x32_bf16(ea[i], pb[j], z, 0, 0, 0);
#pragma unroll
      for (int r = 0; r < 4; ++r) {
        float fc = acc[i][j][r] - SHIFT;
        float pc = rd[r] - ep[r];
        if (fc > 0.f) {
          pos_s = fmaf(fc, pc, pos_s);
          posc += 1.f;
        } else if (fc < 0.f) {
          neg_s = fmaf(fc, pc, neg_s);
          negc += 1.f;
        }
      }
    }
  }
#pragma unroll
  for (int m = 32; m >= 1; m >>= 1) {
    pos_s += __shfl_xor(pos_s, m, 64);
    neg_s += __shfl_xor(neg_s, m, 64);
    posc += __shfl_xor(posc, m, 64);
    negc += __shfl_xor(negc, m, 64);
  }
  if (lane == 0) {
    int bid = (blockIdx.z * 16 + blockIdx.y) * 8 + blockIdx.x;
    *(float4*)(&partials[(bid * 4 + wave) * 4]) = make_float4(pos_s, neg_s, posc, negc);
  }
}

__global__ __launch_bounds__(256) void k_final(const float* __restrict__ partials,
                                               float* __restrict__ out) {
  int tid = threadIdx.x;
  float4 s = make_float4(0.f, 0.f, 0.f, 0.f);
#pragma unroll
  for (int i = 0; i < 8; ++i) {
    float4 v = ((const float4*)partials)[tid + i * 256];
    s.x += v.x;
    s.y += v.y;
    s.z += v.z;
    s.w += v.w;
  }
#pragma unroll
  for (int m = 32; m >= 1; m >>= 1) {
    s.x += __shfl_xor(s.x, m, 64);
    s.y += __shfl_xor(s.y, m, 64);
    s.z += __shfl_xor(s.z, m, 64);
    s.w += __shfl_xor(s.w, m, 64);
  }
  __shared__ float4 red[4];
  if ((tid & 63) == 0) red[tid >> 6] = s;
  __syncthreads();
  if (tid == 0) {
    float4 t = red[0];
#pragma unroll
    for (int w = 1; w < 4; ++w) {
      t.x += red[w].x;
      t.y += red[w].y;
      t.z += red[w].z;
      t.w += red[w].w;
    }
    out[0] = t.x / t.z;
    out[1] = t.y / t.w;
  }
}

extern "C" void kernel_launch(void* const* d_in, const int* in_sizes, int n_in,
                              void* d_out, int out_size, void* d_ws, size_t ws_size,
                              hipStream_t stream) {
  const float* f = (const float*)d_in[0];  // feats [4,32,32,384] f32
  const float* p = (const float*)d_in[1];  // p_class [4,32,32,32] f32 (log-probs)
  float* out = (float*)d_out;              // [pos, neg]
  float* ws = (float*)d_ws;
  // ws layout (floats): rowdot @0 (4096) | partials @4096 (8192 = 2048 waves x4) |
  // fnb @12288 (786432) | Eb @798720 (65536) | Pb @864256 (65536)
  float* rowdot = ws;
  float* partials = ws + 4096;
  unsigned int* fnb = (unsigned int*)(ws + 12288);
  unsigned int* Eb = (unsigned int*)(ws + 798720);
  unsigned int* Pb = (unsigned int*)(ws + 864256);

  k_prep<<<dim3(1088), dim3(256), 0, stream>>>(f, p, fnb, Eb, Pb, rowdot);
  k_pair<<<dim3(8, 16, 4), dim3(256), 0, stream>>>((const unsigned short*)fnb,
                                                   (const unsigned short*)Eb,
                                                   (const unsigned short*)Pb, rowdot, partials);
  k_final<<<dim3(1), dim3(256), 0, stream>>>(partials, out);
}

// Round 7
// 71.089 us; speedup vs baseline: 1.1500x; 1.1500x over previous
//
#include <hip/hip_runtime.h>
#include <hip/hip_bf16.h>

#define S 1024
#define C 384
#define NC 32
#define SHIFT 0.3f

typedef __attribute__((ext_vector_type(4))) float f32x4;
typedef __attribute__((ext_vector_type(8))) short short8;

// f32 -> bf16 (round-to-nearest-even), raw-bit version (finite inputs only)
__device__ __forceinline__ unsigned int f2bf(float x) {
  unsigned int u = __builtin_bit_cast(unsigned int, x);
  unsigned int rb = ((u >> 16) & 1u) + 0x7fffu;
  return (u + rb) >> 16;
}
__device__ __forceinline__ unsigned int f2bf2(float lo, float hi) {
  return f2bf(lo) | (f2bf(hi) << 16);
}

// async global->LDS, 16B per lane; LDS dest is wave-uniform base + lane*16
__device__ __forceinline__ void gld16(void* lds, const void* g) {
  __builtin_amdgcn_global_load_lds(
      (const __attribute__((address_space(1))) void*)g,
      (__attribute__((address_space(3))) void*)lds, 16, 0, 0);
}

// ---- prep: normalize f -> bf16 fnb; exp(p)/p -> bf16 Eb/Pb; rowdot ----
__global__ __launch_bounds__(256) void k_prep(const float* __restrict__ f,
                                              const float* __restrict__ p,
                                              unsigned int* __restrict__ fnb,
                                              unsigned int* __restrict__ Eb,
                                              unsigned int* __restrict__ Pb,
                                              float* __restrict__ rowdot) {
  if (blockIdx.x < 1024) {
    int lane = threadIdx.x & 63;
    int row = blockIdx.x * 4 + (threadIdx.x >> 6);
    const float* fr = f + (size_t)row * C;
    float2 v[3];
    float ss = 0.f;
#pragma unroll
    for (int j = 0; j < 3; ++j) {
      v[j] = *(const float2*)(fr + 2 * lane + 128 * j);
      ss = fmaf(v[j].x, v[j].x, fmaf(v[j].y, v[j].y, ss));
    }
#pragma unroll
    for (int m = 32; m >= 1; m >>= 1) ss += __shfl_xor(ss, m, 64);
    float s = 1.f / fmaxf(sqrtf(ss), 1e-12f);
    unsigned int* outr = fnb + (size_t)row * (C / 2);
#pragma unroll
    for (int j = 0; j < 3; ++j) outr[lane + 64 * j] = f2bf2(v[j].x * s, v[j].y * s);
  } else {
    int t = (blockIdx.x - 1024) * 256 + threadIdx.x;  // [0, 16384)
    int r = t >> 2, q = t & 3;
    const float* pr = p + (size_t)r * NC + q * 8;
    float4 a = *(const float4*)pr;
    float4 b = *(const float4*)(pr + 4);
    float ea0 = __expf(a.x), ea1 = __expf(a.y), ea2 = __expf(a.z), ea3 = __expf(a.w);
    float eb0 = __expf(b.x), eb1 = __expf(b.y), eb2 = __expf(b.z), eb3 = __expf(b.w);
    uint4 ue = make_uint4(f2bf2(ea0, ea1), f2bf2(ea2, ea3), f2bf2(eb0, eb1), f2bf2(eb2, eb3));
    uint4 up = make_uint4(f2bf2(a.x, a.y), f2bf2(a.z, a.w), f2bf2(b.x, b.y), f2bf2(b.z, b.w));
    *(uint4*)(Eb + r * 16 + q * 4) = ue;
    *(uint4*)(Pb + r * 16 + q * 4) = up;
    float s = ea0 * a.x + ea1 * a.y + ea2 * a.z + ea3 * a.w +
              eb0 * b.x + eb1 * b.y + eb2 * b.z + eb3 * b.w;
    s += __shfl_xor(s, 1, 64);
    s += __shfl_xor(s, 2, 64);
    if (q == 0) rowdot[r] = s;
  }
}

// ---- pairwise, TRIANGULAR tiling: 64x64 tiles, only tx>=ty (136 tiles/batch) ----
// f_corr is symmetric -> each unordered pair computed once:
//   s<l: contrib fc*(pc[s,l]+pc[l,s]), count 2;  s==l: fc*pc[s,s], count 1.
// pc[s,l] = rd_s - dot(ea_s, p_l) (EP1);  pc[l,s] = rd_l - dot(ea_l, p_s) (EP2).
// wave w owns output rows [16w,16w+16), all 64 cols. LDS XOR-swizzle as R5.
__global__ __launch_bounds__(256, 4) void k_pair(
    const unsigned short* __restrict__ fnb, const unsigned short* __restrict__ Eb,
    const unsigned short* __restrict__ Pb, const float* __restrict__ rowdot,
    float* __restrict__ partials) {
  __shared__ unsigned short As[64 * 64];
  __shared__ unsigned short Bs[64 * 64];
  __shared__ unsigned short Ese[64 * 40];  // ea for s rows (padded rows)
  __shared__ unsigned short Esp[64 * 40];  // p  for s rows
  __shared__ unsigned short Ele[64 * 40];  // ea for l rows
  __shared__ unsigned short Elp[64 * 40];  // p  for l rows

  const int tid = threadIdx.x;
  const int lane = tid & 63;
  const int wave = tid >> 6;
  const int lan = lane & 15, quad = lane >> 4;
  const int n = blockIdx.y;

  // decode triangular tile index: bx -> (ty, tx) with tx >= ty
  int rem = blockIdx.x, ty = 0;
  while (rem >= 16 - ty) {
    rem -= 16 - ty;
    ++ty;
  }
  const int tx = ty + rem;
  const int sBase = ty * 64;
  const int lBase = tx * 64;

  // per-lane swizzled global source addresses for A/B staging (8 rows per gld16)
  const int r8 = lane >> 3, c8 = lane & 7;
  const char* gA = (const char*)fnb +
                   ((size_t)(n * S + sBase + 16 * wave + r8)) * 768 + ((c8 ^ r8) << 4);
  const char* gB = (const char*)fnb +
                   ((size_t)(n * S + lBase + 16 * wave + r8)) * 768 + ((c8 ^ r8) << 4);
  char* lA = (char*)As + (16 * wave) * 128;
  char* lB = (char*)Bs + (16 * wave) * 128;

  // stage E/P for both row sets (covered by first barrier)
  {
    int row = tid >> 2, q = tid & 3;
    *(uint4*)(&Ese[row * 40 + q * 8]) =
        *(const uint4*)(Eb + (size_t)(n * S + sBase + row) * 32 + q * 8);
    *(uint4*)(&Esp[row * 40 + q * 8]) =
        *(const uint4*)(Pb + (size_t)(n * S + sBase + row) * 32 + q * 8);
    *(uint4*)(&Ele[row * 40 + q * 8]) =
        *(const uint4*)(Eb + (size_t)(n * S + lBase + row) * 32 + q * 8);
    *(uint4*)(&Elp[row * 40 + q * 8]) =
        *(const uint4*)(Pb + (size_t)(n * S + lBase + row) * 32 + q * 8);
  }

  f32x4 acc[4];
#pragma unroll
  for (int j = 0; j < 4; ++j) acc[j] = (f32x4){0.f, 0.f, 0.f, 0.f};

  // K loop: 6 chunks of BK=64; per wave: 4 gld16 stage + 8 MFMA
  for (int kt = 0; kt < 6; ++kt) {
    gld16(lA, gA + kt * 128);
    gld16(lA + 8 * 128, gA + 8 * 768 + kt * 128);
    gld16(lB, gB + kt * 128);
    gld16(lB + 8 * 128, gB + 8 * 768 + kt * 128);
    __syncthreads();
#pragma unroll
    for (int ks = 0; ks < 2; ++ks) {
      short8 af, bfr[4];
      {
        int rowA = 16 * wave + lan;
        af = *(const short8*)((const char*)As + rowA * 128 +
                              ((((ks << 2) | quad) ^ (lan & 7)) << 4));
      }
#pragma unroll
      for (int t = 0; t < 4; ++t) {
        int rowB = t * 16 + lan;
        bfr[t] = *(const short8*)((const char*)Bs + rowB * 128 +
                                  ((((ks << 2) | quad) ^ (lan & 7)) << 4));
      }
#pragma unroll
      for (int j = 0; j < 4; ++j)
        acc[j] = __builtin_amdgcn_mfma_f32_16x16x32_bf16(af, bfr[j], acc[j], 0, 0, 0);
    }
    __syncthreads();
  }

  // epilogue: dual EP mini-GEMMs + weighted triangular reduction
  // C/D layout: row(m=s) = quad*4+reg, col(n=l) = lan
  short8 eas, ps;
  {
    int row = 16 * wave + lan;
    eas = *(const short8*)(&Ese[row * 40 + quad * 8]);
    ps = *(const short8*)(&Esp[row * 40 + quad * 8]);
  }
  float rd_s[4];
  {
    int gs0 = n * S + sBase + 16 * wave + quad * 4;
#pragma unroll
    for (int r = 0; r < 4; ++r) rd_s[r] = rowdot[gs0 + r];
  }

  float pos_s = 0.f, neg_s = 0.f, posc = 0.f, negc = 0.f;
#pragma unroll
  for (int j = 0; j < 4; ++j) {
    short8 pl = *(const short8*)(&Elp[(j * 16 + lan) * 40 + quad * 8]);
    short8 eal = *(const short8*)(&Ele[(j * 16 + lan) * 40 + quad * 8]);
    f32x4 z = (f32x4){0.f, 0.f, 0.f, 0.f};
    f32x4 ep1 = __builtin_amdgcn_mfma_f32_16x16x32_bf16(eas, pl, z, 0, 0, 0);
    f32x4 ep2 = __builtin_amdgcn_mfma_f32_16x16x32_bf16(ps, eal, z, 0, 0, 0);
    int gl = lBase + j * 16 + lan;
    float rd_l = rowdot[n * S + gl];
#pragma unroll
    for (int r = 0; r < 4; ++r) {
      int gs = sBase + 16 * wave + quad * 4 + r;
      float w1 = (gl >= gs) ? 1.f : 0.f;
      float w2 = (gl > gs) ? 1.f : 0.f;
      float fc = acc[j][r] - SHIFT;
      float contrib = w1 * (rd_s[r] - ep1[r]) + w2 * (rd_l - ep2[r]);
      float cnt = w1 + w2;
      if (fc > 0.f) {
        pos_s = fmaf(fc, contrib, pos_s);
        posc += cnt;
      } else if (fc < 0.f) {
        neg_s = fmaf(fc, contrib, neg_s);
        negc += cnt;
      }
    }
  }
#pragma unroll
  for (int m = 32; m >= 1; m >>= 1) {
    pos_s += __shfl_xor(pos_s, m, 64);
    neg_s += __shfl_xor(neg_s, m, 64);
    posc += __shfl_xor(posc, m, 64);
    negc += __shfl_xor(negc, m, 64);
  }
  if (lane == 0) {
    int bid = n * 136 + blockIdx.x;
    *(float4*)(&partials[(bid * 4 + wave) * 4]) = make_float4(pos_s, neg_s, posc, negc);
  }
}

__global__ __launch_bounds__(256) void k_final(const float* __restrict__ partials,
                                               float* __restrict__ out) {
  int tid = threadIdx.x;
  float4 s = make_float4(0.f, 0.f, 0.f, 0.f);
#pragma unroll
  for (int i = 0; i < 9; ++i) {
    int idx = tid + i * 256;
    if (idx < 2176) {
      float4 v = ((const float4*)partials)[idx];
      s.x += v.x;
      s.y += v.y;
      s.z += v.z;
      s.w += v.w;
    }
  }
#pragma unroll
  for (int m = 32; m >= 1; m >>= 1) {
    s.x += __shfl_xor(s.x, m, 64);
    s.y += __shfl_xor(s.y, m, 64);
    s.z += __shfl_xor(s.z, m, 64);
    s.w += __shfl_xor(s.w, m, 64);
  }
  __shared__ float4 red[4];
  if ((tid & 63) == 0) red[tid >> 6] = s;
  __syncthreads();
  if (tid == 0) {
    float4 t = red[0];
#pragma unroll
    for (int w = 1; w < 4; ++w) {
      t.x += red[w].x;
      t.y += red[w].y;
      t.z += red[w].z;
      t.w += red[w].w;
    }
    out[0] = t.x / t.z;
    out[1] = t.y / t.w;
  }
}

extern "C" void kernel_launch(void* const* d_in, const int* in_sizes, int n_in,
                              void* d_out, int out_size, void* d_ws, size_t ws_size,
                              hipStream_t stream) {
  const float* f = (const float*)d_in[0];  // feats [4,32,32,384] f32
  const float* p = (const float*)d_in[1];  // p_class [4,32,32,32] f32 (log-probs)
  float* out = (float*)d_out;              // [pos, neg]
  float* ws = (float*)d_ws;
  // ws layout (floats): rowdot @0 (4096) | partials @4096 (2176*4=8704, pad) |
  // fnb @16384 (786432) | Eb @802816 (65536) | Pb @868352 (65536)
  float* rowdot = ws;
  float* partials = ws + 4096;
  unsigned int* fnb = (unsigned int*)(ws + 16384);
  unsigned int* Eb = (unsigned int*)(ws + 802816);
  unsigned int* Pb = (unsigned int*)(ws + 868352);

  k_prep<<<dim3(1088), dim3(256), 0, stream>>>(f, p, fnb, Eb, Pb, rowdot);
  k_pair<<<dim3(136, 4), dim3(256), 0, stream>>>((const unsigned short*)fnb,
                                                 (const unsigned short*)Eb,
                                                 (const unsigned short*)Pb, rowdot, partials);
  k_final<<<dim3(1), dim3(256), 0, stream>>>(partials, out);
}